// Round 4
// baseline (395.226 us; speedup 1.0000x reference)
//
#include <hip/hip_runtime.h>
#include <math.h>

// ---------------------------------------------------------------------------
// SABlock: x[B,C,H,W] -> depthwise3x3+res -> [B,N,C]: LN1 -> QKV -> flash-MHA
//          -> proj +res -> LN2 -> FC1 -> GELU -> FC2 -> +res -> [B,C,H,W]
// R10: fc2 ported to a pipelined counted-vmcnt GEMM (128x192 tile, grid 256
// = exactly one round; triple-buffered LDS, prefetch distance 2 K-tiles,
// one s_waitcnt vmcnt(5) per K-tile -- never drains across 48 K-steps).
// NCHW epilogue kept (resid+bias, [64][132] f32 bounce, 3 slices).
// fc1 keeps R9's 256x192 4-phase kernel. QKV/proj keep gemm_bt. FA unchanged.
// ---------------------------------------------------------------------------

typedef __bf16 bf16;
typedef __attribute__((ext_vector_type(8))) __bf16 bf16x8;
typedef __attribute__((ext_vector_type(4))) __bf16 bf16x4;
typedef __attribute__((ext_vector_type(4))) float f32x4;

#define B_   8
#define C_   768
#define N_   1024
#define NH_  12
#define HD_  64
#define HID_ 3072
#define NTOK   (B_ * N_)     // 8192
#define NHEADS (B_ * NH_)    // 96
#define FA_C   0.1803368801111601f  // 0.125 * log2(e)

__device__ __forceinline__ void gload_lds16(const void* g, void* l) {
  __builtin_amdgcn_global_load_lds(
      (__attribute__((address_space(1))) void*)(void*)g,
      (__attribute__((address_space(3))) void*)l, 16, 0, 0);
}

__device__ __forceinline__ float gelu1(float x) {
  // tanh-form GELU via exp2; |err| well under bf16 noise (verified R4/R5)
  float u = 0.7978845608028654f * x * (1.0f + 0.044715f * x * x);
  float e = __builtin_amdgcn_exp2f(u * 2.885390081777927f);  // exp(2u)
  float th = 1.0f - 2.0f * __builtin_amdgcn_rcpf(e + 1.0f);
  return 0.5f * x * (1.0f + th);
}

// counted-vmcnt phase boundary: NO vmcnt(0) drain (raw barrier, not
// __syncthreads). lgkmcnt(0) closes the WAR window at LDS buffer flips.
// asm memory clobber = IR-level fence; sched_barrier(0) = MIR-level fence.
#define PIPE_SYNC(N)                                              \
  do {                                                            \
    asm volatile("s_waitcnt vmcnt(" #N ") lgkmcnt(0)" ::: "memory"); \
    __builtin_amdgcn_sched_barrier(0);                            \
    __builtin_amdgcn_s_barrier();                                 \
    __builtin_amdgcn_sched_barrier(0);                            \
    asm volatile("" ::: "memory");                                \
  } while (0)

// ---------------------------------------------------------------------------
// fc2: 128x192-tile pipelined B^T GEMM, K=3072 (48 tiles), NCHW epilogue.
// Grid 256 = 64 m x 4 n = exactly ONE round at 1 block/CU (no tail).
// 512 thr = 8 waves (2 Wm x 4 Wc); wave tile 64x48 (4 m-frags x 3 n-frags).
// LDS: 3 buffers x (A 16KB + B 24KB) = 120 KB; prefetch distance 2 K-tiles:
// during tile t, issue tile t+2's 5 chunks (B0,B1,B2,A0,A1).
// vmcnt accounting: at tile-t entry, outstanding = tile t+1's 5 loads
// (issued during t-1) -> PIPE_SYNC(5) retires tile t's set exactly; the
// queue is never drained in the main loop. Loads get ~2 K-tiles of compute
// to land. WAR: write buf[(t+2)%3] = buf[(t-1)%3], last read in tile t-1;
// per-tile lgkmcnt(0)+barrier orders it. Last tile peeled with vmcnt(0).
// Swizzle: chunk slot = c ^ (row&7) (0 bank conflicts, proven R5).
// REMAP: bid&7 = XCD owns 8 m-tiles x all 4 n-tiles.
// Epilogue: out[b][chan][tok] = resid + acc + bias via [64][132] f32 bounce,
// 3 sequential 64-chan slices reusing staging LDS.
// ---------------------------------------------------------------------------
__global__ __launch_bounds__(512) void gemm_fc2(
    const bf16* __restrict__ A, const bf16* __restrict__ Bw,
    const float* __restrict__ bias, const float* __restrict__ resid,
    float* __restrict__ outp, int K, int lda, int ldb) {
  __shared__ __align__(16) char smem[122880];
  const int tid = threadIdx.x;
  const int wave = tid >> 6, lane = tid & 63;
  const int wr = wave & 1, wc = wave >> 1;
  const int lr = lane & 15, kq = lane >> 4;

  const int bid = blockIdx.x;
  const int g = bid & 7, s = bid >> 3;
  const int ms = s >> 2;                 // 0..7
  const int m0 = (g * 8 + ms) * 128;
  const int n0 = (s & 3) * 192;

  f32x4 acc[4][3];
#pragma unroll
  for (int i = 0; i < 4; ++i)
#pragma unroll
    for (int j = 0; j < 3; ++j) acc[i][j] = (f32x4){0.f, 0.f, 0.f, 0.f};

  // staging pointers: A = 2 chunks (rows 0..127), B = 3 chunks (rows 0..191)
  const bf16* pa[2];
  const bf16* pb[3];
  int da[2], db[3];
#pragma unroll
  for (int c = 0; c < 2; ++c) {
    const int sidx = c * 512 + tid;
    const int r = sidx >> 3, seg = (sidx & 7) ^ (r & 7);
    pa[c] = A + (size_t)(m0 + r) * lda + seg * 8;
    da[c] = sidx * 16;
  }
#pragma unroll
  for (int c = 0; c < 3; ++c) {
    const int sidx = c * 512 + tid;
    const int r = sidx >> 3, seg = (sidx & 7) ^ (r & 7);
    pb[c] = Bw + (size_t)(n0 + r) * ldb + seg * 8;
    db[c] = 16384 + sidx * 16;
  }

  const int NT = K >> 6;  // 48

  // prologue: stage tiles 0 (buf0) and 1 (buf1); 10 loads in flight
#pragma unroll
  for (int tt = 0; tt < 2; ++tt) {
    char* wb = smem + tt * 40960;
    gload_lds16(pb[0], wb + db[0]);
    gload_lds16(pb[1], wb + db[1]);
    gload_lds16(pb[2], wb + db[2]);
    gload_lds16(pa[0], wb + da[0]);
    gload_lds16(pa[1], wb + da[1]);
    pb[0] += 64; pb[1] += 64; pb[2] += 64; pa[0] += 64; pa[1] += 64;
  }

  int cur = 0;
  for (int t = 0; t < NT - 1; ++t) {
    const char* rb = smem + cur * 40960;
    PIPE_SYNC(5);
    if (t < NT - 2) {
      int wi = cur + 2; if (wi >= 3) wi -= 3;
      char* wb = smem + wi * 40960;
      gload_lds16(pb[0], wb + db[0]); pb[0] += 64;
      gload_lds16(pb[1], wb + db[1]); pb[1] += 64;
      gload_lds16(pb[2], wb + db[2]); pb[2] += 64;
      gload_lds16(pa[0], wb + da[0]); pa[0] += 64;
      gload_lds16(pa[1], wb + da[1]); pa[1] += 64;
    }
    bf16x8 af[4], bf[3];
    // ---- k-half 0
#pragma unroll
    for (int i = 0; i < 4; ++i) {
      const int r = wr * 64 + i * 16 + lr;
      af[i] = *(const bf16x8*)(rb + (r * 8 + (kq ^ (r & 7))) * 16);
    }
#pragma unroll
    for (int j = 0; j < 3; ++j) {
      const int r = wc * 48 + j * 16 + lr;
      bf[j] = *(const bf16x8*)(rb + 16384 + (r * 8 + (kq ^ (r & 7))) * 16);
    }
    __builtin_amdgcn_s_setprio(1);
#pragma unroll
    for (int i = 0; i < 4; ++i)
#pragma unroll
      for (int j = 0; j < 3; ++j)
        acc[i][j] = __builtin_amdgcn_mfma_f32_16x16x32_bf16(bf[j], af[i],
                                                            acc[i][j], 0, 0, 0);
    __builtin_amdgcn_s_setprio(0);
    // ---- k-half 1
#pragma unroll
    for (int i = 0; i < 4; ++i) {
      const int r = wr * 64 + i * 16 + lr;
      af[i] = *(const bf16x8*)(rb + (r * 8 + ((4 + kq) ^ (r & 7))) * 16);
    }
#pragma unroll
    for (int j = 0; j < 3; ++j) {
      const int r = wc * 48 + j * 16 + lr;
      bf[j] = *(const bf16x8*)(rb + 16384 + (r * 8 + ((4 + kq) ^ (r & 7))) * 16);
    }
    __builtin_amdgcn_s_setprio(1);
#pragma unroll
    for (int i = 0; i < 4; ++i)
#pragma unroll
      for (int j = 0; j < 3; ++j)
        acc[i][j] = __builtin_amdgcn_mfma_f32_16x16x32_bf16(bf[j], af[i],
                                                            acc[i][j], 0, 0, 0);
    __builtin_amdgcn_s_setprio(0);
    if (++cur == 3) cur = 0;
  }

  {  // ---- last K-tile, peeled: full drain, no staging
    const char* rb = smem + cur * 40960;
    bf16x8 af[4], bf[3];
    PIPE_SYNC(0);
#pragma unroll
    for (int kh = 0; kh < 2; ++kh) {
      const int c0 = kh * 4 + kq;
#pragma unroll
      for (int i = 0; i < 4; ++i) {
        const int r = wr * 64 + i * 16 + lr;
        af[i] = *(const bf16x8*)(rb + (r * 8 + (c0 ^ (r & 7))) * 16);
      }
#pragma unroll
      for (int j = 0; j < 3; ++j) {
        const int r = wc * 48 + j * 16 + lr;
        bf[j] = *(const bf16x8*)(rb + 16384 + (r * 8 + (c0 ^ (r & 7))) * 16);
      }
      __builtin_amdgcn_s_setprio(1);
#pragma unroll
      for (int i = 0; i < 4; ++i)
#pragma unroll
        for (int j = 0; j < 3; ++j)
          acc[i][j] = __builtin_amdgcn_mfma_f32_16x16x32_bf16(bf[j], af[i],
                                                              acc[i][j], 0, 0, 0);
      __builtin_amdgcn_s_setprio(0);
    }
  }

  // epilogue: out[b][chan][tok] = resid + acc + bias, 3 x 64-chan slices
  {
    float* tile = (float*)smem;
    const int b = m0 >> 10, tok0 = m0 & (N_ - 1);
#pragma unroll
    for (int sl = 0; sl < 3; ++sl) {
      __syncthreads();
#pragma unroll
      for (int j = 0; j < 3; ++j) {
        const int nl0 = wc * 48 + j * 16 + kq * 4;
        if (((wc * 48 + j * 16) >> 6) == sl) {   // wave-uniform
          const int n = n0 + nl0;
          const f32x4 bv = *(const f32x4*)(bias + n);
#pragma unroll
          for (int i = 0; i < 4; ++i) {
            const int ml = wr * 64 + i * 16 + lr;
            const float* rp = resid + (size_t)(m0 + ml) * C_ + n;
            f32x4 old = *(const f32x4*)rp;
            const f32x4 v = acc[i][j];
#pragma unroll
            for (int r = 0; r < 4; ++r)
              tile[(nl0 - sl * 64 + r) * 132 + ml] = old[r] + v[r] + bv[r];
          }
        }
      }
      __syncthreads();
      const int nl = tid & 63, mc = tid >> 6;   // 64 chans x 8 m-chunks of 16
      float* dst = outp + ((size_t)(b * C_ + n0 + sl * 64 + nl)) * N_ +
                   tok0 + mc * 16;
      const float* src = tile + nl * 132 + mc * 16;
#pragma unroll
      for (int q = 0; q < 4; ++q)
        *(f32x4*)(dst + q * 4) = *(const f32x4*)(src + q * 4);
    }
  }
}

// ---------------------------------------------------------------------------
// fc1: 256x192-tile pipelined B^T GEMM + GELU epilogue.
// Grid 512 = 32 m-tiles x 16 n-tiles = EXACTLY 2 rounds at 1 block/CU.
// 512 thr = 8 waves (2 Wm x 4 Wn); wave tile 128x48 (8 m-frags x 3 n-frags).
// BK=64; LDS = 2 x (A 32KB + B 24KB) = 112 KB double-buffered.
// Staging: A = 4 chunks/thread (rows 64c..64c+63), B = 3 chunks/thread.
// Per K-tile, 4 phases; issue plan (tile t+1): [ph0: B0,B1 | ph1: B2,A0 |
// ph2: A1,A2 | ph3: A3]; waits vmcnt(1)/(2)/(4)/(6). Last tile peeled
// with vmcnt(0). Swizzle: chunk slot = c ^ (row&7) (0 conflicts).
// REMAP: bid&7 = XCD owns mtpx m-tiles x all n-tiles.
// ---------------------------------------------------------------------------
__global__ __launch_bounds__(512) void gemm_fc1(
    const bf16* __restrict__ A, const bf16* __restrict__ Bw,
    const float* __restrict__ bias, bf16* __restrict__ outp,
    int K, int lda, int ldb, int ntiles, int mtpx, int ldo) {
  __shared__ __align__(16) char smem[114688];
  const int tid = threadIdx.x;
  const int wave = tid >> 6, lane = tid & 63;
  const int wr = wave & 1, wc = wave >> 1;
  const int lr = lane & 15, kq = lane >> 4;

  const int bid = blockIdx.x;
  const int g = bid & 7, s = bid >> 3;
  const int ms = s / ntiles;
  const int m0 = (g * mtpx + ms) * 256;
  const int n0 = (s - ms * ntiles) * 192;

  f32x4 acc[8][3];
#pragma unroll
  for (int i = 0; i < 8; ++i)
#pragma unroll
    for (int j = 0; j < 3; ++j) acc[i][j] = (f32x4){0.f, 0.f, 0.f, 0.f};

  // staging pointers: A chunks c cover rows [64c,64c+64), full K-row each
  const bf16* pa[4];
  const bf16* pb[3];
  int da[4], db[3];
#pragma unroll
  for (int c = 0; c < 4; ++c) {
    const int sidx = c * 512 + tid;
    const int r = sidx >> 3, seg = (sidx & 7) ^ (r & 7);
    pa[c] = A + (size_t)(m0 + r) * lda + seg * 8;
    da[c] = sidx * 16;
  }
#pragma unroll
  for (int c = 0; c < 3; ++c) {
    const int sidx = c * 512 + tid;
    const int r = sidx >> 3, seg = (sidx & 7) ^ (r & 7);
    pb[c] = Bw + (size_t)(n0 + r) * ldb + seg * 8;
    db[c] = 32768 + sidx * 16;
  }

  const int NT = K >> 6;

  // prologue: tile 0 -> buf0, order B0 B1 B2 A0 A1 A2 A3 (A3 newest ->
  // vmcnt(1) at t=0 ph0 leaves exactly A3 in flight, needed first at ph1)
  gload_lds16(pb[0], smem + db[0]);
  gload_lds16(pb[1], smem + db[1]);
  gload_lds16(pb[2], smem + db[2]);
  gload_lds16(pa[0], smem + da[0]);
  gload_lds16(pa[1], smem + da[1]);
  gload_lds16(pa[2], smem + da[2]);
  gload_lds16(pa[3], smem + da[3]);
#pragma unroll
  for (int c = 0; c < 4; ++c) pa[c] += 64;
#pragma unroll
  for (int c = 0; c < 3; ++c) pb[c] += 64;

  for (int t = 0; t < NT - 1; ++t) {
    const char* rb = smem + (t & 1) * 57344;
    char* wb = smem + ((t & 1) ^ 1) * 57344;
    bf16x8 af[4], bf0[3], bf1[3];

    // ---- ph0: k0 x m-rows[0..63 of half] + all B k0; stage B0,B1
    PIPE_SYNC(1);
#pragma unroll
    for (int i = 0; i < 4; ++i) {
      const int r = wr * 128 + i * 16 + lr;
      af[i] = *(const bf16x8*)(rb + (r * 8 + (kq ^ (r & 7))) * 16);
    }
#pragma unroll
    for (int j = 0; j < 3; ++j) {
      const int r = wc * 48 + j * 16 + lr;
      bf0[j] = *(const bf16x8*)(rb + 32768 + (r * 8 + (kq ^ (r & 7))) * 16);
    }
    gload_lds16(pb[0], wb + db[0]); pb[0] += 64;
    gload_lds16(pb[1], wb + db[1]); pb[1] += 64;
    __builtin_amdgcn_s_setprio(1);
#pragma unroll
    for (int i = 0; i < 4; ++i)
#pragma unroll
      for (int j = 0; j < 3; ++j)
        acc[i][j] = __builtin_amdgcn_mfma_f32_16x16x32_bf16(bf0[j], af[i],
                                                            acc[i][j], 0, 0, 0);
    __builtin_amdgcn_s_setprio(0);

    // ---- ph1: k0 x m-rows[64..127 of half]; stage B2,A0
    PIPE_SYNC(2);
#pragma unroll
    for (int i = 0; i < 4; ++i) {
      const int r = wr * 128 + 64 + i * 16 + lr;
      af[i] = *(const bf16x8*)(rb + (r * 8 + (kq ^ (r & 7))) * 16);
    }
    gload_lds16(pb[2], wb + db[2]); pb[2] += 64;
    gload_lds16(pa[0], wb + da[0]); pa[0] += 64;
    __builtin_amdgcn_s_setprio(1);
#pragma unroll
    for (int i = 0; i < 4; ++i)
#pragma unroll
      for (int j = 0; j < 3; ++j)
        acc[4 + i][j] = __builtin_amdgcn_mfma_f32_16x16x32_bf16(
            bf0[j], af[i], acc[4 + i][j], 0, 0, 0);
    __builtin_amdgcn_s_setprio(0);

    // ---- ph2: k1 x m-rows[0..63 of half] + all B k1; stage A1,A2
    PIPE_SYNC(4);
#pragma unroll
    for (int i = 0; i < 4; ++i) {
      const int r = wr * 128 + i * 16 + lr;
      af[i] = *(const bf16x8*)(rb + (r * 8 + ((4 + kq) ^ (r & 7))) * 16);
    }
#pragma unroll
    for (int j = 0; j < 3; ++j) {
      const int r = wc * 48 + j * 16 + lr;
      bf1[j] = *(const bf16x8*)(rb + 32768 + (r * 8 + ((4 + kq) ^ (r & 7))) * 16);
    }
    gload_lds16(pa[1], wb + da[1]); pa[1] += 64;
    gload_lds16(pa[2], wb + da[2]); pa[2] += 64;
    __builtin_amdgcn_s_setprio(1);
#pragma unroll
    for (int i = 0; i < 4; ++i)
#pragma unroll
      for (int j = 0; j < 3; ++j)
        acc[i][j] = __builtin_amdgcn_mfma_f32_16x16x32_bf16(bf1[j], af[i],
                                                            acc[i][j], 0, 0, 0);
    __builtin_amdgcn_s_setprio(0);

    // ---- ph3: k1 x m-rows[64..127 of half]; stage A3
    PIPE_SYNC(6);
#pragma unroll
    for (int i = 0; i < 4; ++i) {
      const int r = wr * 128 + 64 + i * 16 + lr;
      af[i] = *(const bf16x8*)(rb + (r * 8 + ((4 + kq) ^ (r & 7))) * 16);
    }
    gload_lds16(pa[3], wb + da[3]); pa[3] += 64;
    __builtin_amdgcn_s_setprio(1);
#pragma unroll
    for (int i = 0; i < 4; ++i)
#pragma unroll
      for (int j = 0; j < 3; ++j)
        acc[4 + i][j] = __builtin_amdgcn_mfma_f32_16x16x32_bf16(
            bf1[j], af[i], acc[4 + i][j], 0, 0, 0);
    __builtin_amdgcn_s_setprio(0);
  }

  {  // ---- last K-tile, peeled: full drain, no barriers, no staging
    const char* rb = smem + ((NT - 1) & 1) * 57344;
    bf16x8 af[4], bf0[3], bf1[3];
    PIPE_SYNC(0);
#pragma unroll
    for (int j = 0; j < 3; ++j) {
      const int r = wc * 48 + j * 16 + lr;
      bf0[j] = *(const bf16x8*)(rb + 32768 + (r * 8 + (kq ^ (r & 7))) * 16);
      bf1[j] = *(const bf16x8*)(rb + 32768 + (r * 8 + ((4 + kq) ^ (r & 7))) * 16);
    }
    __builtin_amdgcn_s_setprio(1);
#pragma unroll
    for (int half = 0; half < 2; ++half) {
#pragma unroll
      for (int i = 0; i < 4; ++i) {
        const int r = wr * 128 + half * 64 + i * 16 + lr;
        af[i] = *(const bf16x8*)(rb + (r * 8 + (kq ^ (r & 7))) * 16);
      }
#pragma unroll
      for (int i = 0; i < 4; ++i)
#pragma unroll
        for (int j = 0; j < 3; ++j)
          acc[half * 4 + i][j] = __builtin_amdgcn_mfma_f32_16x16x32_bf16(
              bf0[j], af[i], acc[half * 4 + i][j], 0, 0, 0);
#pragma unroll
      for (int i = 0; i < 4; ++i) {
        const int r = wr * 128 + half * 64 + i * 16 + lr;
        af[i] = *(const bf16x8*)(rb + (r * 8 + ((4 + kq) ^ (r & 7))) * 16);
      }
#pragma unroll
      for (int i = 0; i < 4; ++i)
#pragma unroll
        for (int j = 0; j < 3; ++j)
          acc[half * 4 + i][j] = __builtin_amdgcn_mfma_f32_16x16x32_bf16(
              bf1[j], af[i], acc[half * 4 + i][j], 0, 0, 0);
    }
    __builtin_amdgcn_s_setprio(0);
  }

  // epilogue: GELU(acc + bias) -> bf16
#pragma unroll
  for (int j = 0; j < 3; ++j) {
    const int n = n0 + wc * 48 + j * 16 + kq * 4;
    const f32x4 bv = *(const f32x4*)(bias + n);
#pragma unroll
    for (int i = 0; i < 8; ++i) {
      const int m = m0 + wr * 128 + i * 16 + lr;
      const f32x4 v = acc[i][j];
      bf16x4 pk = {(bf16)gelu1(v[0] + bv[0]), (bf16)gelu1(v[1] + bv[1]),
                   (bf16)gelu1(v[2] + bv[2]), (bf16)gelu1(v[3] + bv[3])};
      *(bf16x4*)(outp + (size_t)m * ldo + n) = pk;
    }
  }
}

// ---------------------------------------------------------------------------
// B^T GEMM, 128xBN tile, BK=64, 256 thr (2x2 waves; wave-tile 64 x BN/2).
// Transposed accumulators (operand-swapped MFMA): lane holds C[m][n..n+3],
//   m = m0+wm*64+i*16+lr,  n = n0+wn*(BN/2)+j*16+kq*4,  j < BN/32
// LDS: rows of 8 x 16B chunks, chunk slot = c ^ (row&7) -> 0 bank conflicts.
// REMAP: 1-D grid; xcd g = bid&7 owns m-stripes [8g,8g+8) x all ntiles
//        n-tiles (A-stripe pinned to one XCD's L2).
// EPI: 0 = QKV (Q,K vector stores; V via LDS bounce -> V^T rows)
//      3 = resid float4 RMW += v + bias
// ---------------------------------------------------------------------------
template <int BN, int EPI, bool REMAP>
__global__ __launch_bounds__(256) void gemm_bt(
    const bf16* __restrict__ A, const bf16* __restrict__ B, int K, int lda,
    int ldb, int ntiles, bf16* __restrict__ o0, bf16* __restrict__ o1,
    bf16* __restrict__ o2, float* __restrict__ resid,
    const float* __restrict__ bias, float* __restrict__ outp) {
  constexpr int JJ = BN / 32;                      // j-tiles per wave
  constexpr int BCH = BN / 32;                     // B staging chunks/thread
  constexpr int STAGE_B = (128 + BN) * 64 * 2;
  constexpr int EXTRA_B = (EPI == 0 ? 128 * 256 : 0);
  constexpr int SMEM_B = STAGE_B > EXTRA_B ? STAGE_B : EXTRA_B;
  __shared__ __align__(16) char smemraw[SMEM_B];
  bf16* As = (bf16*)smemraw;
  bf16* Bs = As + 128 * 64;

  const int tid = threadIdx.x;
  const int wave = tid >> 6, lane = tid & 63;
  const int wm = wave & 1, wn = wave >> 1;
  const int lr = lane & 15, kq = lane >> 4;
  const int sw = lr & 7;

  int m0, n0;
  if constexpr (REMAP) {
    const int bid = blockIdx.x;
    const int g = bid & 7, s = bid >> 3;
    const int ms = s / ntiles;
    m0 = (g * 8 + ms) * 128;
    n0 = (s - ms * ntiles) * BN;
  } else {
    m0 = blockIdx.y * 128;
    n0 = blockIdx.x * BN;
  }

  f32x4 acc[4][JJ];
#pragma unroll
  for (int i = 0; i < 4; i++)
#pragma unroll
    for (int j = 0; j < JJ; j++) acc[i][j] = (f32x4){0.f, 0.f, 0.f, 0.f};

  // hoisted per-thread staging addresses (advance by 64 elems per K-iter)
  const bf16* ap[4];
  const bf16* bp[BCH];
  {
    const bf16* Arow = A + (size_t)m0 * lda;
    const bf16* Brow = B + (size_t)n0 * ldb;
#pragma unroll
    for (int it = 0; it < 4; ++it) {
      int s = it * 256 + tid;
      int r = s >> 3, seg = (s & 7) ^ (r & 7);
      ap[it] = Arow + (size_t)r * lda + seg * 8;
    }
#pragma unroll
    for (int it = 0; it < BCH; ++it) {
      int s = it * 256 + tid;
      int r = s >> 3, seg = (s & 7) ^ (r & 7);
      bp[it] = Brow + (size_t)r * ldb + seg * 8;
    }
  }

  for (int k0 = 0; k0 < K; k0 += 64) {
#pragma unroll
    for (int it = 0; it < 4; ++it) {
      gload_lds16(ap[it], (char*)As + (it * 256 + tid) * 16);
      ap[it] += 64;
    }
#pragma unroll
    for (int it = 0; it < BCH; ++it) {
      gload_lds16(bp[it], (char*)Bs + (it * 256 + tid) * 16);
      bp[it] += 64;
    }
    __syncthreads();

#pragma unroll
    for (int h = 0; h < 2; ++h) {
      bf16x8 af[4], bfr[JJ];
      const int c = h * 4 + kq;
#pragma unroll
      for (int i = 0; i < 4; i++) {
        int row = wm * 64 + i * 16 + lr;
        af[i] = *(const bf16x8*)((char*)As + (row * 8 + (c ^ sw)) * 16);
      }
#pragma unroll
      for (int j = 0; j < JJ; j++) {
        int row = wn * (BN / 2) + j * 16 + lr;
        bfr[j] = *(const bf16x8*)((char*)Bs + (row * 8 + (c ^ sw)) * 16);
      }
      // swapped operands -> transposed C/D layout
#pragma unroll
      for (int i = 0; i < 4; i++)
#pragma unroll
        for (int j = 0; j < JJ; j++)
          acc[i][j] = __builtin_amdgcn_mfma_f32_16x16x32_bf16(bfr[j], af[i],
                                                              acc[i][j], 0, 0, 0);
    }
    __syncthreads();
  }

  if constexpr (EPI == 0) {
    const int b = m0 >> 10, tok0 = m0 & (N_ - 1);
    if (n0 < 2 * C_) {
      // Q or K: vector bf16x4 stores, [head][tok][d]
      const int s = n0 >= C_ ? 1 : 0;
      bf16* dst = s ? o1 : o0;
#pragma unroll
      for (int i = 0; i < 4; i++) {
        const int m = m0 + wm * 64 + i * 16 + lr;
#pragma unroll
        for (int j = 0; j < JJ; j++) {
          const int rem = n0 - s * C_ + wn * (BN / 2) + j * 16 + kq * 4;
          const int h = rem >> 6, d = rem & 63;
          const f32x4 v = acc[i][j];
          bf16x4 pk = {(bf16)v[0], (bf16)v[1], (bf16)v[2], (bf16)v[3]};
          size_t head = (size_t)b * NH_ + h;
          *(bf16x4*)(dst + (head * N_ + (m & (N_ - 1))) * HD_ + d) = pk;
        }
      }
    } else {
      // V: bounce through LDS (swizzled) -> coalesced V^T rows
      bf16* tile = (bf16*)smemraw;
#pragma unroll
      for (int i = 0; i < 4; i++) {
        const int ml = wm * 64 + i * 16 + lr;
        const int mc = ml >> 3, mo = ml & 7;
#pragma unroll
        for (int j = 0; j < JJ; j++) {
          const f32x4 v = acc[i][j];
#pragma unroll
          for (int r = 0; r < 4; r++) {
            const int nl = wn * (BN / 2) + j * 16 + kq * 4 + r;
            *(bf16*)((char*)tile + nl * 256 + ((mc ^ (nl & 15)) * 16) + mo * 2) =
                (bf16)v[r];
          }
        }
      }
      __syncthreads();
      const int nl = tid >> 1, mh = (tid & 1) * 64;   // 128 rows x 2 halves
      const int vb = n0 - 2 * C_ + nl;                // channel within 768
      const size_t head = (size_t)b * NH_ + (vb >> 6);
      bf16* dst = o2 + (head * HD_ + (vb & 63)) * N_ + tok0 + mh;
#pragma unroll
      for (int c8 = 0; c8 < 8; ++c8) {
        const int c = (mh >> 3) + c8;
        bf16x8 val = *(const bf16x8*)((char*)tile + nl * 256 +
                                      ((c ^ (nl & 15)) * 16));
        *(bf16x8*)(dst + c8 * 8) = val;
      }
    }
  } else if constexpr (EPI == 3) {
#pragma unroll
    for (int j = 0; j < JJ; j++) {
      const int n = n0 + wn * (BN / 2) + j * 16 + kq * 4;
      const f32x4 bv = *(const f32x4*)(bias + n);
#pragma unroll
      for (int i = 0; i < 4; i++) {
        const int m = m0 + wm * 64 + i * 16 + lr;
        float* rp = resid + (size_t)m * C_ + n;
        f32x4 old = *(const f32x4*)rp;
        const f32x4 v = acc[i][j];
        f32x4 nw = {old[0] + v[0] + bv[0], old[1] + v[1] + bv[1],
                    old[2] + v[2] + bv[2], old[3] + v[3] + bv[3]};
        *(f32x4*)rp = nw;
      }
    }
  }
}

// ---------------------------------------------------------------------------
// Flash attention: grid (8 q-tiles, 96 heads) = 768 blocks, 256 thr.
// Wave owns 32 q-rows. 16 K-tiles of 64, double-buffered staging.
// ---------------------------------------------------------------------------
__global__ __launch_bounds__(256, 3) void flash_attn(
    const bf16* __restrict__ Qb, const bf16* __restrict__ Kb,
    const bf16* __restrict__ Vt, bf16* __restrict__ attn) {
  __shared__ __align__(16) bf16 ksm[2][64 * 64];
  __shared__ __align__(16) bf16 vsm[2][64 * 64];
  __shared__ __align__(16) bf16 psm[4][32 * 64];

  const int tid = threadIdx.x, wave = tid >> 6, lane = tid & 63;
  const int lr = lane & 15, kq = lane >> 4;
  const int head = blockIdx.y;
  const int b = head / NH_, hh = head - b * NH_;
  const int q0 = blockIdx.x * 128;
  const bf16* Qh = Qb + (size_t)head * (N_ * HD_);
  const bf16* Kh = Kb + (size_t)head * (N_ * HD_);
  const bf16* Vh = Vt + (size_t)head * (HD_ * N_);
  char* pw = (char*)&psm[wave][0];

  bf16x8 qf[2][2];
#pragma unroll
  for (int j = 0; j < 2; ++j)
#pragma unroll
    for (int kh = 0; kh < 2; ++kh)
      qf[j][kh] = *(const bf16x8*)(Qh +
                                   (size_t)(q0 + wave * 32 + j * 16 + lr) * HD_ +
                                   kh * 32 + kq * 8);

  f32x4 o[4][2];
#pragma unroll
  for (int i = 0; i < 4; i++)
#pragma unroll
    for (int j = 0; j < 2; j++) o[i][j] = (f32x4){0.f, 0.f, 0.f, 0.f};
  float mprev[2] = {-1e30f, -1e30f}, lacc[2] = {0.f, 0.f};

  auto stage = [&](int t, int bi) {
#pragma unroll
    for (int it = 0; it < 2; ++it) {
      int s = it * 256 + tid;
      int r = s >> 3, seg = (s & 7) ^ (r & 7);
      gload_lds16(Kh + (size_t)(t * 64 + r) * HD_ + seg * 8,
                  (char*)ksm[bi] + (it * 256 + wave * 64) * 16);
    }
#pragma unroll
    for (int it = 0; it < 2; ++it) {
      int s = it * 256 + tid;
      int r = s >> 3, seg = (s & 7) ^ (r & 7);
      gload_lds16(Vh + (size_t)r * N_ + t * 64 + seg * 8,
                  (char*)vsm[bi] + (it * 256 + wave * 64) * 16);
    }
  };

  stage(0, 0);

  for (int t = 0; t < 16; ++t) {
    const int bi = t & 1;
    __syncthreads();
    if (t < 15) stage(t + 1, bi ^ 1);

    f32x4 sacc[4][2];
#pragma unroll
    for (int i = 0; i < 4; ++i) {
#pragma unroll
      for (int j = 0; j < 2; ++j) sacc[i][j] = (f32x4){0.f, 0.f, 0.f, 0.f};
      int row = i * 16 + lr;
      bf16x8 kf0 = *(const bf16x8*)((char*)ksm[bi] + row * 128 +
                                    ((kq ^ (row & 7)) * 16));
      bf16x8 kf1 = *(const bf16x8*)((char*)ksm[bi] + row * 128 +
                                    (((4 + kq) ^ (row & 7)) * 16));
#pragma unroll
      for (int j = 0; j < 2; ++j) {
        sacc[i][j] = __builtin_amdgcn_mfma_f32_16x16x32_bf16(kf0, qf[j][0],
                                                             sacc[i][j], 0, 0, 0);
        sacc[i][j] = __builtin_amdgcn_mfma_f32_16x16x32_bf16(kf1, qf[j][1],
                                                             sacc[i][j], 0, 0, 0);
      }
    }

#pragma unroll
    for (int j = 0; j < 2; ++j) {
      float mx = -1e30f;
#pragma unroll
      for (int i = 0; i < 4; ++i)
#pragma unroll
        for (int r = 0; r < 4; ++r) mx = fmaxf(mx, sacc[i][j][r]);
      mx = fmaxf(mx, __shfl_xor(mx, 16));
      mx = fmaxf(mx, __shfl_xor(mx, 32));
      float mnew = fmaxf(mprev[j], mx);
      float alpha = __builtin_amdgcn_exp2f((mprev[j] - mnew) * FA_C);
      mprev[j] = mnew;
      float rs = 0.f;
      const int prow = j * 16 + lr;
#pragma unroll
      for (int i = 0; i < 4; ++i) {
        float p0 = __builtin_amdgcn_exp2f((sacc[i][j][0] - mnew) * FA_C);
        float p1 = __builtin_amdgcn_exp2f((sacc[i][j][1] - mnew) * FA_C);
        float p2 = __builtin_amdgcn_exp2f((sacc[i][j][2] - mnew) * FA_C);
        float p3 = __builtin_amdgcn_exp2f((sacc[i][j][3] - mnew) * FA_C);
        rs += (p0 + p1) + (p2 + p3);
        bf16x4 pk = {(bf16)p0, (bf16)p1, (bf16)p2, (bf16)p3};
        int c = i * 2 + (kq >> 1);
        *(bf16x4*)(pw + prow * 128 + ((c ^ (prow & 7)) * 16) + (kq & 1) * 8) = pk;
      }
      rs += __shfl_xor(rs, 16);
      rs += __shfl_xor(rs, 32);
      lacc[j] = lacc[j] * alpha + rs;
#pragma unroll
      for (int i = 0; i < 4; ++i) {
        o[i][j][0] *= alpha; o[i][j][1] *= alpha;
        o[i][j][2] *= alpha; o[i][j][3] *= alpha;
      }
    }

#pragma unroll
    for (int k0c = 0; k0c < 2; ++k0c) {
      bf16x8 pf[2];
#pragma unroll
      for (int j = 0; j < 2; ++j) {
        int prow = j * 16 + lr, c = k0c * 4 + kq;
        pf[j] = *(const bf16x8*)(pw + prow * 128 + ((c ^ (prow & 7)) * 16));
      }
#pragma unroll
      for (int i = 0; i < 4; ++i) {
        int d = i * 16 + lr, c = k0c * 4 + kq;
        bf16x8 vf = *(const bf16x8*)((char*)vsm[bi] + d * 128 +
                                     ((c ^ (d & 7)) * 16));
#pragma unroll
        for (int j = 0; j < 2; ++j)
          o[i][j] = __builtin_amdgcn_mfma_f32_16x16x32_bf16(vf, pf[j], o[i][j],
                                                            0, 0, 0);
      }
    }
  }

#pragma unroll
  for (int j = 0; j < 2; ++j) {
    float inv = 1.0f / lacc[j];
    int tok = q0 + wave * 32 + j * 16 + lr;
    bf16* op = attn + ((size_t)(b * N_ + tok)) * C_ + hh * HD_;
#pragma unroll
    for (int i = 0; i < 4; ++i) {
      bf16x4 pk = {(bf16)(o[i][j][0] * inv), (bf16)(o[i][j][1] * inv),
                   (bf16)(o[i][j][2] * inv), (bf16)(o[i][j][3] * inv)};
      *(bf16x4*)(op + i * 16 + kq * 4) = pk;
    }
  }
}

// ---------------------------------------------------------------------------
__global__ __launch_bounds__(256) void cast_all(
    const float* __restrict__ a, int na, const float* __restrict__ b, int nb,
    const float* __restrict__ c, int nc, const float* __restrict__ d,
    bf16* __restrict__ dst) {
  int i = (blockIdx.x * 256 + threadIdx.x) * 4;
  const float* src;
  int off;
  if (i < na) { src = a; off = i; }
  else if (i < na + nb) { src = b; off = i - na; }
  else if (i < na + nb + nc) { src = c; off = i - na - nb; }
  else { src = d; off = i - na - nb - nc; }
  float4 v = *(const float4*)(src + off);
  bf16x4 o = {(bf16)v.x, (bf16)v.y, (bf16)v.z, (bf16)v.w};
  *(bf16x4*)(dst + i) = o;
}

// depthwise 3x3 conv + bias + residual, fused transpose NCHW -> [B,N,C]
__global__ __launch_bounds__(256) void conv_pe_t(const float* __restrict__ x,
                                                 const float* __restrict__ cw,
                                                 const float* __restrict__ cb,
                                                 float* __restrict__ t0) {
  __shared__ float tile[32][33];
  const int h = blockIdx.x, ct = blockIdx.y, b = blockIdx.z;
  const int tid = threadIdx.x;
  const int w = tid & 31, cs = tid >> 5;
#pragma unroll
  for (int cc = cs; cc < 32; cc += 8) {
    int c = ct * 32 + cc;
    const float* xp = x + ((size_t)(b * C_ + c)) * 1024;
    const float* wp = cw + c * 9;
    float s = cb[c] + xp[h * 32 + w];
#pragma unroll
    for (int ky = 0; ky < 3; ++ky) {
      int hy = h + ky - 1;
      if ((unsigned)hy < 32u) {
#pragma unroll
        for (int kx = 0; kx < 3; ++kx) {
          int wx = w + kx - 1;
          if ((unsigned)wx < 32u) s += xp[hy * 32 + wx] * wp[ky * 3 + kx];
        }
      }
    }
    tile[cc][w] = s;
  }
  __syncthreads();
  const int cc = tid & 31;
#pragma unroll
  for (int wc = tid >> 5; wc < 32; wc += 8)
    t0[((size_t)(b * N_) + h * 32 + wc) * C_ + ct * 32 + cc] = tile[cc][wc];
}

// LayerNorm over C=768, fp32 in, bf16 out
__global__ __launch_bounds__(256) void ln_bf16(const float* __restrict__ t,
                                               const float* __restrict__ g,
                                               const float* __restrict__ be,
                                               bf16* __restrict__ out) {
  int row = blockIdx.x, tid = threadIdx.x;
  const float* p = t + (size_t)row * C_;
  float v0 = p[tid], v1 = p[tid + 256], v2 = p[tid + 512];
  __shared__ float rs[256], rq[256];
  rs[tid] = v0 + v1 + v2;
  rq[tid] = v0 * v0 + v1 * v1 + v2 * v2;
  __syncthreads();
  for (int off = 128; off; off >>= 1) {
    if (tid < off) {
      rs[tid] += rs[tid + off];
      rq[tid] += rq[tid + off];
    }
    __syncthreads();
  }
  float mu = rs[0] * (1.f / C_);
  float var = rq[0] * (1.f / C_) - mu * mu;
  float rstd = rsqrtf(var + 1e-5f);
  bf16* q = out + (size_t)row * C_;
  q[tid] = (bf16)((v0 - mu) * rstd * g[tid] + be[tid]);
  q[tid + 256] = (bf16)((v1 - mu) * rstd * g[tid + 256] + be[tid + 256]);
  q[tid + 512] = (bf16)((v2 - mu) * rstd * g[tid + 512] + be[tid + 512]);
}

// ---------------------------------------------------------------------------
extern "C" void kernel_launch(void* const* d_in, const int* in_sizes, int n_in,
                              void* d_out, int out_size, void* d_ws,
                              size_t ws_size, hipStream_t stream) {
  (void)in_sizes; (void)n_in; (void)out_size; (void)ws_size;
  const float* x      = (const float*)d_in[0];
  const float* conv_w = (const float*)d_in[1];
  const float* conv_b = (const float*)d_in[2];
  const float* ln1_g  = (const float*)d_in[3];
  const float* ln1_b  = (const float*)d_in[4];
  const float* qkv_w  = (const float*)d_in[5];
  const float* proj_w = (const float*)d_in[6];
  const float* proj_b = (const float*)d_in[7];
  const float* ln2_g  = (const float*)d_in[8];
  const float* ln2_b  = (const float*)d_in[9];
  const float* fc1_w  = (const float*)d_in[10];
  const float* fc1_b  = (const float*)d_in[11];
  const float* fc2_w  = (const float*)d_in[12];
  const float* fc2_b  = (const float*)d_in[13];
  float* out = (float*)d_out;

  char* w = (char*)d_ws;
  auto carve = [&](size_t bytes) {
    char* p = w;
    w += (bytes + 255) & ~(size_t)255;
    return p;
  };
  bf16* hid   = (bf16*)carve((size_t)NTOK * HID_ * 2);
  float* t0   = (float*)carve((size_t)NTOK * C_ * 4);
  bf16* lnout = (bf16*)carve((size_t)NTOK * C_ * 2);
  bf16* wq    = (bf16*)carve((size_t)3 * C_ * C_ * 2);
  bf16* wp    = (bf16*)carve((size_t)C_ * C_ * 2);
  bf16* w1    = (bf16*)carve((size_t)HID_ * C_ * 2);
  bf16* w2    = (bf16*)carve((size_t)C_ * HID_ * 2);
  bf16* Qb    = (bf16*)carve((size_t)NHEADS * N_ * HD_ * 2);
  bf16* Kb    = (bf16*)carve((size_t)NHEADS * N_ * HD_ * 2);
  bf16* Vt    = (bf16*)carve((size_t)NHEADS * HD_ * N_ * 2);
  bf16* attn  = (bf16*)carve((size_t)NTOK * C_ * 2);

  const int na = 3 * C_ * C_, nb = C_ * C_, nc = HID_ * C_, nd = C_ * HID_;
  cast_all<<<(na + nb + nc + nd) / 1024, 256, 0, stream>>>(
      qkv_w, na, proj_w, nb, fc1_w, nc, fc2_w, wq);

  conv_pe_t<<<dim3(32, C_ / 32, B_), 256, 0, stream>>>(x, conv_w, conv_b, t0);

  // QKV: 18 n-tiles x 64 m-stripes, XCD remap
  ln_bf16<<<NTOK, 256, 0, stream>>>(t0, ln1_g, ln1_b, lnout);
  gemm_bt<128, 0, true><<<1152, 256, 0, stream>>>(
      lnout, wq, 768, 768, 768, 18, Qb, Kb, Vt, nullptr, nullptr, nullptr);

  flash_attn<<<dim3(N_ / 128, NHEADS), 256, 0, stream>>>(Qb, Kb, Vt, attn);

  // proj: 12 n-tiles (BN=64); fc1: 256x192 pipelined (512 blocks = 2 rounds);
  // fc2: 128x192 pipelined (256 blocks = 1 round), NCHW epilogue
  gemm_bt<64, 3, true><<<768, 256, 0, stream>>>(
      attn, wp, 768, 768, 768, 12, nullptr, nullptr, nullptr, t0, proj_b,
      nullptr);
  ln_bf16<<<NTOK, 256, 0, stream>>>(t0, ln2_g, ln2_b, lnout);
  gemm_fc1<<<512, 512, 0, stream>>>(lnout, w1, fc1_b, hid, 768, 768, 768,
                                    16, 4, HID_);
  gemm_fc2<<<256, 512, 0, stream>>>(hid, w2, fc2_b, t0, out, 3072, 3072, 3072);
}

// Round 5
// 386.186 us; speedup vs baseline: 1.0234x; 1.0234x over previous
//
#include <hip/hip_runtime.h>
#include <math.h>

// ---------------------------------------------------------------------------
// SABlock: x[B,C,H,W] -> depthwise3x3+res -> [B,N,C]: LN1 -> QKV -> flash-MHA
//          -> proj +res -> LN2 -> FC1 -> GELU -> FC2 -> +res -> [B,C,H,W]
// R11: fc2 restructured to the faithful m201 phase cadence: per K-tile =
// entry{vmcnt(5)+bar} -> 2x phase{ds_read frags; stage; bar; lgkmcnt(0);
// setprio MFMA cluster; bar}. Reads hoisted BEFORE the barrier (latency
// drains in barrier-wait); MFMA cluster isolated between barriers; vmcnt
// counted once per tile (distance-2 tribuf). fc1 left IDENTICAL as the
// in-run control (both were ~56us in R10). QKV/proj keep gemm_bt. FA same.
// ---------------------------------------------------------------------------

typedef __bf16 bf16;
typedef __attribute__((ext_vector_type(8))) __bf16 bf16x8;
typedef __attribute__((ext_vector_type(4))) __bf16 bf16x4;
typedef __attribute__((ext_vector_type(4))) float f32x4;

#define B_   8
#define C_   768
#define N_   1024
#define NH_  12
#define HD_  64
#define HID_ 3072
#define NTOK   (B_ * N_)     // 8192
#define NHEADS (B_ * NH_)    // 96
#define FA_C   0.1803368801111601f  // 0.125 * log2(e)

__device__ __forceinline__ void gload_lds16(const void* g, void* l) {
  __builtin_amdgcn_global_load_lds(
      (__attribute__((address_space(1))) void*)(void*)g,
      (__attribute__((address_space(3))) void*)l, 16, 0, 0);
}

__device__ __forceinline__ float gelu1(float x) {
  // tanh-form GELU via exp2; |err| well under bf16 noise (verified R4/R5)
  float u = 0.7978845608028654f * x * (1.0f + 0.044715f * x * x);
  float e = __builtin_amdgcn_exp2f(u * 2.885390081777927f);  // exp(2u)
  float th = 1.0f - 2.0f * __builtin_amdgcn_rcpf(e + 1.0f);
  return 0.5f * x * (1.0f + th);
}

// counted-vmcnt phase boundary (R9-style, used by fc1): vmcnt+lgkm BEFORE
// the barrier; reads issue after.
#define PIPE_SYNC(N)                                              \
  do {                                                            \
    asm volatile("s_waitcnt vmcnt(" #N ") lgkmcnt(0)" ::: "memory"); \
    __builtin_amdgcn_sched_barrier(0);                            \
    __builtin_amdgcn_s_barrier();                                 \
    __builtin_amdgcn_sched_barrier(0);                            \
    asm volatile("" ::: "memory");                                \
  } while (0)

// m201-cadence fences (used by fc2)
#define BAR_FENCED()                                              \
  do {                                                            \
    __builtin_amdgcn_sched_barrier(0);                            \
    __builtin_amdgcn_s_barrier();                                 \
    __builtin_amdgcn_sched_barrier(0);                            \
  } while (0)
#define LGKM0()                                                   \
  do {                                                            \
    asm volatile("s_waitcnt lgkmcnt(0)" ::: "memory");            \
    __builtin_amdgcn_sched_barrier(0);                            \
  } while (0)

// ---------------------------------------------------------------------------
// fc2: 128x192-tile pipelined B^T GEMM, K=3072 (48 tiles), NCHW epilogue.
// Grid 256 = 64 m x 4 n = exactly ONE round at 1 block/CU (no tail).
// 512 thr = 8 waves (2 Wm x 4 Wc); wave tile 64x48 (4 m-frags x 3 n-frags).
// LDS: 3 buffers x (A 16KB + B 24KB) = 120 KB; prefetch distance 2 K-tiles.
// m201 cadence per K-tile:
//   entry: vmcnt(5) [retire tile t's 5 chunks; leave t+1's 5 in flight]
//          + barrier  => whole rb tile readable by every wave after this.
//   ph0:   ds_read k0 frags (7 b128) ; stage B0,B1,B2 -> wb(t+2) ;
//          barrier ; lgkmcnt(0) ; setprio(1) 12 MFMA setprio(0) ; barrier
//   ph1:   ds_read k1 frags (7)     ; stage A0,A1 -> wb ;
//          barrier ; lgkmcnt(0) ; setprio(1) 12 MFMA setprio(0) ; barrier
// Reads-before-barrier are safe: covered by this tile's entry vmcnt+barrier
// (distance-2 => all of rb landed at entry). WAR on wb (= buffer last read
// at tile t-1): every wave passed t-1 ph1's END barrier only after its own
// lgkmcnt(0), so all reads of that buffer completed before any t-ph0 stage.
// Last tile peeled with vmcnt(0). Swizzle: slot = c ^ (row&7) (0 conflicts).
// REMAP: bid&7 = XCD owns 8 m-tiles x all 4 n-tiles.
// Epilogue: out[b][chan][tok] = resid + acc + bias via [64][132] f32 bounce.
// ---------------------------------------------------------------------------
__global__ __launch_bounds__(512) void gemm_fc2(
    const bf16* __restrict__ A, const bf16* __restrict__ Bw,
    const float* __restrict__ bias, const float* __restrict__ resid,
    float* __restrict__ outp, int K, int lda, int ldb) {
  __shared__ __align__(16) char smem[122880];
  const int tid = threadIdx.x;
  const int wave = tid >> 6, lane = tid & 63;
  const int wr = wave & 1, wc = wave >> 1;
  const int lr = lane & 15, kq = lane >> 4;

  const int bid = blockIdx.x;
  const int g = bid & 7, s = bid >> 3;
  const int ms = s >> 2;                 // 0..7
  const int m0 = (g * 8 + ms) * 128;
  const int n0 = (s & 3) * 192;

  f32x4 acc[4][3];
#pragma unroll
  for (int i = 0; i < 4; ++i)
#pragma unroll
    for (int j = 0; j < 3; ++j) acc[i][j] = (f32x4){0.f, 0.f, 0.f, 0.f};

  // staging pointers: A = 2 chunks (rows 0..127), B = 3 chunks (rows 0..191)
  const bf16* pa[2];
  const bf16* pb[3];
  int da[2], db[3];
#pragma unroll
  for (int c = 0; c < 2; ++c) {
    const int sidx = c * 512 + tid;
    const int r = sidx >> 3, seg = (sidx & 7) ^ (r & 7);
    pa[c] = A + (size_t)(m0 + r) * lda + seg * 8;
    da[c] = sidx * 16;
  }
#pragma unroll
  for (int c = 0; c < 3; ++c) {
    const int sidx = c * 512 + tid;
    const int r = sidx >> 3, seg = (sidx & 7) ^ (r & 7);
    pb[c] = Bw + (size_t)(n0 + r) * ldb + seg * 8;
    db[c] = 16384 + sidx * 16;
  }

  const int NT = K >> 6;  // 48

  // prologue: stage tiles 0 (buf0) and 1 (buf1); 10 loads in flight
#pragma unroll
  for (int tt = 0; tt < 2; ++tt) {
    char* wb = smem + tt * 40960;
    gload_lds16(pb[0], wb + db[0]);
    gload_lds16(pb[1], wb + db[1]);
    gload_lds16(pb[2], wb + db[2]);
    gload_lds16(pa[0], wb + da[0]);
    gload_lds16(pa[1], wb + da[1]);
    pb[0] += 64; pb[1] += 64; pb[2] += 64; pa[0] += 64; pa[1] += 64;
  }

  int cur = 0;
  for (int t = 0; t < NT - 1; ++t) {
    const char* rb = smem + cur * 40960;
    int wi = cur + 2; if (wi >= 3) wi -= 3;
    char* wb = smem + wi * 40960;
    const bool dostage = (t < NT - 2);

    // ---- tile entry: retire tile t's 5 loads; sync (rb fully readable)
    asm volatile("s_waitcnt vmcnt(5) lgkmcnt(0)" ::: "memory");
    BAR_FENCED();

    bf16x8 af[4], bf[3];
    // ---- ph0: k-half 0 -------------------------------------------------
#pragma unroll
    for (int i = 0; i < 4; ++i) {
      const int r = wr * 64 + i * 16 + lr;
      af[i] = *(const bf16x8*)(rb + (r * 8 + (kq ^ (r & 7))) * 16);
    }
#pragma unroll
    for (int j = 0; j < 3; ++j) {
      const int r = wc * 48 + j * 16 + lr;
      bf[j] = *(const bf16x8*)(rb + 16384 + (r * 8 + (kq ^ (r & 7))) * 16);
    }
    if (dostage) {
      gload_lds16(pb[0], wb + db[0]); pb[0] += 64;
      gload_lds16(pb[1], wb + db[1]); pb[1] += 64;
      gload_lds16(pb[2], wb + db[2]); pb[2] += 64;
    }
    BAR_FENCED();
    LGKM0();
    __builtin_amdgcn_s_setprio(1);
#pragma unroll
    for (int i = 0; i < 4; ++i)
#pragma unroll
      for (int j = 0; j < 3; ++j)
        acc[i][j] = __builtin_amdgcn_mfma_f32_16x16x32_bf16(bf[j], af[i],
                                                            acc[i][j], 0, 0, 0);
    __builtin_amdgcn_s_setprio(0);
    BAR_FENCED();

    // ---- ph1: k-half 1 -------------------------------------------------
#pragma unroll
    for (int i = 0; i < 4; ++i) {
      const int r = wr * 64 + i * 16 + lr;
      af[i] = *(const bf16x8*)(rb + (r * 8 + ((4 + kq) ^ (r & 7))) * 16);
    }
#pragma unroll
    for (int j = 0; j < 3; ++j) {
      const int r = wc * 48 + j * 16 + lr;
      bf[j] = *(const bf16x8*)(rb + 16384 + (r * 8 + ((4 + kq) ^ (r & 7))) * 16);
    }
    if (dostage) {
      gload_lds16(pa[0], wb + da[0]); pa[0] += 64;
      gload_lds16(pa[1], wb + da[1]); pa[1] += 64;
    }
    BAR_FENCED();
    LGKM0();
    __builtin_amdgcn_s_setprio(1);
#pragma unroll
    for (int i = 0; i < 4; ++i)
#pragma unroll
      for (int j = 0; j < 3; ++j)
        acc[i][j] = __builtin_amdgcn_mfma_f32_16x16x32_bf16(bf[j], af[i],
                                                            acc[i][j], 0, 0, 0);
    __builtin_amdgcn_s_setprio(0);
    BAR_FENCED();

    if (++cur == 3) cur = 0;
  }

  {  // ---- last K-tile, peeled: full drain, no staging
    const char* rb = smem + cur * 40960;
    bf16x8 af[4], bf[3];
    asm volatile("s_waitcnt vmcnt(0) lgkmcnt(0)" ::: "memory");
    BAR_FENCED();
#pragma unroll
    for (int kh = 0; kh < 2; ++kh) {
      const int c0 = kh * 4 + kq;
#pragma unroll
      for (int i = 0; i < 4; ++i) {
        const int r = wr * 64 + i * 16 + lr;
        af[i] = *(const bf16x8*)(rb + (r * 8 + (c0 ^ (r & 7))) * 16);
      }
#pragma unroll
      for (int j = 0; j < 3; ++j) {
        const int r = wc * 48 + j * 16 + lr;
        bf[j] = *(const bf16x8*)(rb + 16384 + (r * 8 + (c0 ^ (r & 7))) * 16);
      }
      __builtin_amdgcn_s_setprio(1);
#pragma unroll
      for (int i = 0; i < 4; ++i)
#pragma unroll
        for (int j = 0; j < 3; ++j)
          acc[i][j] = __builtin_amdgcn_mfma_f32_16x16x32_bf16(bf[j], af[i],
                                                              acc[i][j], 0, 0, 0);
      __builtin_amdgcn_s_setprio(0);
    }
  }

  // epilogue: out[b][chan][tok] = resid + acc + bias, 3 x 64-chan slices
  {
    float* tile = (float*)smem;
    const int b = m0 >> 10, tok0 = m0 & (N_ - 1);
#pragma unroll
    for (int sl = 0; sl < 3; ++sl) {
      __syncthreads();
#pragma unroll
      for (int j = 0; j < 3; ++j) {
        const int nl0 = wc * 48 + j * 16 + kq * 4;
        if (((wc * 48 + j * 16) >> 6) == sl) {   // wave-uniform
          const int n = n0 + nl0;
          const f32x4 bv = *(const f32x4*)(bias + n);
#pragma unroll
          for (int i = 0; i < 4; ++i) {
            const int ml = wr * 64 + i * 16 + lr;
            const float* rp = resid + (size_t)(m0 + ml) * C_ + n;
            f32x4 old = *(const f32x4*)rp;
            const f32x4 v = acc[i][j];
#pragma unroll
            for (int r = 0; r < 4; ++r)
              tile[(nl0 - sl * 64 + r) * 132 + ml] = old[r] + v[r] + bv[r];
          }
        }
      }
      __syncthreads();
      const int nl = tid & 63, mc = tid >> 6;   // 64 chans x 8 m-chunks of 16
      float* dst = outp + ((size_t)(b * C_ + n0 + sl * 64 + nl)) * N_ +
                   tok0 + mc * 16;
      const float* src = tile + nl * 132 + mc * 16;
#pragma unroll
      for (int q = 0; q < 4; ++q)
        *(f32x4*)(dst + q * 4) = *(const f32x4*)(src + q * 4);
    }
  }
}

// ---------------------------------------------------------------------------
// fc1: 256x192-tile pipelined B^T GEMM + GELU epilogue.  (R9 form, UNCHANGED
// this round -- serves as the in-run control against fc2's new cadence.)
// Grid 512 = 32 m-tiles x 16 n-tiles = EXACTLY 2 rounds at 1 block/CU.
// ---------------------------------------------------------------------------
__global__ __launch_bounds__(512) void gemm_fc1(
    const bf16* __restrict__ A, const bf16* __restrict__ Bw,
    const float* __restrict__ bias, bf16* __restrict__ outp,
    int K, int lda, int ldb, int ntiles, int mtpx, int ldo) {
  __shared__ __align__(16) char smem[114688];
  const int tid = threadIdx.x;
  const int wave = tid >> 6, lane = tid & 63;
  const int wr = wave & 1, wc = wave >> 1;
  const int lr = lane & 15, kq = lane >> 4;

  const int bid = blockIdx.x;
  const int g = bid & 7, s = bid >> 3;
  const int ms = s / ntiles;
  const int m0 = (g * mtpx + ms) * 256;
  const int n0 = (s - ms * ntiles) * 192;

  f32x4 acc[8][3];
#pragma unroll
  for (int i = 0; i < 8; ++i)
#pragma unroll
    for (int j = 0; j < 3; ++j) acc[i][j] = (f32x4){0.f, 0.f, 0.f, 0.f};

  // staging pointers: A chunks c cover rows [64c,64c+64), full K-row each
  const bf16* pa[4];
  const bf16* pb[3];
  int da[4], db[3];
#pragma unroll
  for (int c = 0; c < 4; ++c) {
    const int sidx = c * 512 + tid;
    const int r = sidx >> 3, seg = (sidx & 7) ^ (r & 7);
    pa[c] = A + (size_t)(m0 + r) * lda + seg * 8;
    da[c] = sidx * 16;
  }
#pragma unroll
  for (int c = 0; c < 3; ++c) {
    const int sidx = c * 512 + tid;
    const int r = sidx >> 3, seg = (sidx & 7) ^ (r & 7);
    pb[c] = Bw + (size_t)(n0 + r) * ldb + seg * 8;
    db[c] = 32768 + sidx * 16;
  }

  const int NT = K >> 6;

  // prologue: tile 0 -> buf0, order B0 B1 B2 A0 A1 A2 A3
  gload_lds16(pb[0], smem + db[0]);
  gload_lds16(pb[1], smem + db[1]);
  gload_lds16(pb[2], smem + db[2]);
  gload_lds16(pa[0], smem + da[0]);
  gload_lds16(pa[1], smem + da[1]);
  gload_lds16(pa[2], smem + da[2]);
  gload_lds16(pa[3], smem + da[3]);
#pragma unroll
  for (int c = 0; c < 4; ++c) pa[c] += 64;
#pragma unroll
  for (int c = 0; c < 3; ++c) pb[c] += 64;

  for (int t = 0; t < NT - 1; ++t) {
    const char* rb = smem + (t & 1) * 57344;
    char* wb = smem + ((t & 1) ^ 1) * 57344;
    bf16x8 af[4], bf0[3], bf1[3];

    // ---- ph0: k0 x m-rows[0..63 of half] + all B k0; stage B0,B1
    PIPE_SYNC(1);
#pragma unroll
    for (int i = 0; i < 4; ++i) {
      const int r = wr * 128 + i * 16 + lr;
      af[i] = *(const bf16x8*)(rb + (r * 8 + (kq ^ (r & 7))) * 16);
    }
#pragma unroll
    for (int j = 0; j < 3; ++j) {
      const int r = wc * 48 + j * 16 + lr;
      bf0[j] = *(const bf16x8*)(rb + 32768 + (r * 8 + (kq ^ (r & 7))) * 16);
    }
    gload_lds16(pb[0], wb + db[0]); pb[0] += 64;
    gload_lds16(pb[1], wb + db[1]); pb[1] += 64;
    __builtin_amdgcn_s_setprio(1);
#pragma unroll
    for (int i = 0; i < 4; ++i)
#pragma unroll
      for (int j = 0; j < 3; ++j)
        acc[i][j] = __builtin_amdgcn_mfma_f32_16x16x32_bf16(bf0[j], af[i],
                                                            acc[i][j], 0, 0, 0);
    __builtin_amdgcn_s_setprio(0);

    // ---- ph1: k0 x m-rows[64..127 of half]; stage B2,A0
    PIPE_SYNC(2);
#pragma unroll
    for (int i = 0; i < 4; ++i) {
      const int r = wr * 128 + 64 + i * 16 + lr;
      af[i] = *(const bf16x8*)(rb + (r * 8 + (kq ^ (r & 7))) * 16);
    }
    gload_lds16(pb[2], wb + db[2]); pb[2] += 64;
    gload_lds16(pa[0], wb + da[0]); pa[0] += 64;
    __builtin_amdgcn_s_setprio(1);
#pragma unroll
    for (int i = 0; i < 4; ++i)
#pragma unroll
      for (int j = 0; j < 3; ++j)
        acc[4 + i][j] = __builtin_amdgcn_mfma_f32_16x16x32_bf16(
            bf0[j], af[i], acc[4 + i][j], 0, 0, 0);
    __builtin_amdgcn_s_setprio(0);

    // ---- ph2: k1 x m-rows[0..63 of half] + all B k1; stage A1,A2
    PIPE_SYNC(4);
#pragma unroll
    for (int i = 0; i < 4; ++i) {
      const int r = wr * 128 + i * 16 + lr;
      af[i] = *(const bf16x8*)(rb + (r * 8 + ((4 + kq) ^ (r & 7))) * 16);
    }
#pragma unroll
    for (int j = 0; j < 3; ++j) {
      const int r = wc * 48 + j * 16 + lr;
      bf1[j] = *(const bf16x8*)(rb + 32768 + (r * 8 + ((4 + kq) ^ (r & 7))) * 16);
    }
    gload_lds16(pa[1], wb + da[1]); pa[1] += 64;
    gload_lds16(pa[2], wb + da[2]); pa[2] += 64;
    __builtin_amdgcn_s_setprio(1);
#pragma unroll
    for (int i = 0; i < 4; ++i)
#pragma unroll
      for (int j = 0; j < 3; ++j)
        acc[i][j] = __builtin_amdgcn_mfma_f32_16x16x32_bf16(bf1[j], af[i],
                                                            acc[i][j], 0, 0, 0);
    __builtin_amdgcn_s_setprio(0);

    // ---- ph3: k1 x m-rows[64..127 of half]; stage A3
    PIPE_SYNC(6);
#pragma unroll
    for (int i = 0; i < 4; ++i) {
      const int r = wr * 128 + 64 + i * 16 + lr;
      af[i] = *(const bf16x8*)(rb + (r * 8 + ((4 + kq) ^ (r & 7))) * 16);
    }
    gload_lds16(pa[3], wb + da[3]); pa[3] += 64;
    __builtin_amdgcn_s_setprio(1);
#pragma unroll
    for (int i = 0; i < 4; ++i)
#pragma unroll
      for (int j = 0; j < 3; ++j)
        acc[4 + i][j] = __builtin_amdgcn_mfma_f32_16x16x32_bf16(
            bf1[j], af[i], acc[4 + i][j], 0, 0, 0);
    __builtin_amdgcn_s_setprio(0);
  }

  {  // ---- last K-tile, peeled: full drain, no barriers, no staging
    const char* rb = smem + ((NT - 1) & 1) * 57344;
    bf16x8 af[4], bf0[3], bf1[3];
    PIPE_SYNC(0);
#pragma unroll
    for (int j = 0; j < 3; ++j) {
      const int r = wc * 48 + j * 16 + lr;
      bf0[j] = *(const bf16x8*)(rb + 32768 + (r * 8 + (kq ^ (r & 7))) * 16);
      bf1[j] = *(const bf16x8*)(rb + 32768 + (r * 8 + ((4 + kq) ^ (r & 7))) * 16);
    }
    __builtin_amdgcn_s_setprio(1);
#pragma unroll
    for (int half = 0; half < 2; ++half) {
#pragma unroll
      for (int i = 0; i < 4; ++i) {
        const int r = wr * 128 + half * 64 + i * 16 + lr;
        af[i] = *(const bf16x8*)(rb + (r * 8 + (kq ^ (r & 7))) * 16);
      }
#pragma unroll
      for (int i = 0; i < 4; ++i)
#pragma unroll
        for (int j = 0; j < 3; ++j)
          acc[half * 4 + i][j] = __builtin_amdgcn_mfma_f32_16x16x32_bf16(
              bf0[j], af[i], acc[half * 4 + i][j], 0, 0, 0);
#pragma unroll
      for (int i = 0; i < 4; ++i) {
        const int r = wr * 128 + half * 64 + i * 16 + lr;
        af[i] = *(const bf16x8*)(rb + (r * 8 + ((4 + kq) ^ (r & 7))) * 16);
      }
#pragma unroll
      for (int i = 0; i < 4; ++i)
#pragma unroll
        for (int j = 0; j < 3; ++j)
          acc[half * 4 + i][j] = __builtin_amdgcn_mfma_f32_16x16x32_bf16(
              bf1[j], af[i], acc[half * 4 + i][j], 0, 0, 0);
    }
    __builtin_amdgcn_s_setprio(0);
  }

  // epilogue: GELU(acc + bias) -> bf16
#pragma unroll
  for (int j = 0; j < 3; ++j) {
    const int n = n0 + wc * 48 + j * 16 + kq * 4;
    const f32x4 bv = *(const f32x4*)(bias + n);
#pragma unroll
    for (int i = 0; i < 8; ++i) {
      const int m = m0 + wr * 128 + i * 16 + lr;
      const f32x4 v = acc[i][j];
      bf16x4 pk = {(bf16)gelu1(v[0] + bv[0]), (bf16)gelu1(v[1] + bv[1]),
                   (bf16)gelu1(v[2] + bv[2]), (bf16)gelu1(v[3] + bv[3])};
      *(bf16x4*)(outp + (size_t)m * ldo + n) = pk;
    }
  }
}

// ---------------------------------------------------------------------------
// B^T GEMM, 128xBN tile, BK=64, 256 thr (2x2 waves; wave-tile 64 x BN/2).
// Transposed accumulators (operand-swapped MFMA): lane holds C[m][n..n+3],
//   m = m0+wm*64+i*16+lr,  n = n0+wn*(BN/2)+j*16+kq*4,  j < BN/32
// LDS: rows of 8 x 16B chunks, chunk slot = c ^ (row&7) -> 0 bank conflicts.
// REMAP: 1-D grid; xcd g = bid&7 owns m-stripes [8g,8g+8) x all ntiles
//        n-tiles (A-stripe pinned to one XCD's L2).
// EPI: 0 = QKV (Q,K vector stores; V via LDS bounce -> V^T rows)
//      3 = resid float4 RMW += v + bias
// ---------------------------------------------------------------------------
template <int BN, int EPI, bool REMAP>
__global__ __launch_bounds__(256) void gemm_bt(
    const bf16* __restrict__ A, const bf16* __restrict__ B, int K, int lda,
    int ldb, int ntiles, bf16* __restrict__ o0, bf16* __restrict__ o1,
    bf16* __restrict__ o2, float* __restrict__ resid,
    const float* __restrict__ bias, float* __restrict__ outp) {
  constexpr int JJ = BN / 32;                      // j-tiles per wave
  constexpr int BCH = BN / 32;                     // B staging chunks/thread
  constexpr int STAGE_B = (128 + BN) * 64 * 2;
  constexpr int EXTRA_B = (EPI == 0 ? 128 * 256 : 0);
  constexpr int SMEM_B = STAGE_B > EXTRA_B ? STAGE_B : EXTRA_B;
  __shared__ __align__(16) char smemraw[SMEM_B];
  bf16* As = (bf16*)smemraw;
  bf16* Bs = As + 128 * 64;

  const int tid = threadIdx.x;
  const int wave = tid >> 6, lane = tid & 63;
  const int wm = wave & 1, wn = wave >> 1;
  const int lr = lane & 15, kq = lane >> 4;
  const int sw = lr & 7;

  int m0, n0;
  if constexpr (REMAP) {
    const int bid = blockIdx.x;
    const int g = bid & 7, s = bid >> 3;
    const int ms = s / ntiles;
    m0 = (g * 8 + ms) * 128;
    n0 = (s - ms * ntiles) * BN;
  } else {
    m0 = blockIdx.y * 128;
    n0 = blockIdx.x * BN;
  }

  f32x4 acc[4][JJ];
#pragma unroll
  for (int i = 0; i < 4; i++)
#pragma unroll
    for (int j = 0; j < JJ; j++) acc[i][j] = (f32x4){0.f, 0.f, 0.f, 0.f};

  // hoisted per-thread staging addresses (advance by 64 elems per K-iter)
  const bf16* ap[4];
  const bf16* bp[BCH];
  {
    const bf16* Arow = A + (size_t)m0 * lda;
    const bf16* Brow = B + (size_t)n0 * ldb;
#pragma unroll
    for (int it = 0; it < 4; ++it) {
      int s = it * 256 + tid;
      int r = s >> 3, seg = (s & 7) ^ (r & 7);
      ap[it] = Arow + (size_t)r * lda + seg * 8;
    }
#pragma unroll
    for (int it = 0; it < BCH; ++it) {
      int s = it * 256 + tid;
      int r = s >> 3, seg = (s & 7) ^ (r & 7);
      bp[it] = Brow + (size_t)r * ldb + seg * 8;
    }
  }

  for (int k0 = 0; k0 < K; k0 += 64) {
#pragma unroll
    for (int it = 0; it < 4; ++it) {
      gload_lds16(ap[it], (char*)As + (it * 256 + tid) * 16);
      ap[it] += 64;
    }
#pragma unroll
    for (int it = 0; it < BCH; ++it) {
      gload_lds16(bp[it], (char*)Bs + (it * 256 + tid) * 16);
      bp[it] += 64;
    }
    __syncthreads();

#pragma unroll
    for (int h = 0; h < 2; ++h) {
      bf16x8 af[4], bfr[JJ];
      const int c = h * 4 + kq;
#pragma unroll
      for (int i = 0; i < 4; i++) {
        int row = wm * 64 + i * 16 + lr;
        af[i] = *(const bf16x8*)((char*)As + (row * 8 + (c ^ sw)) * 16);
      }
#pragma unroll
      for (int j = 0; j < JJ; j++) {
        int row = wn * (BN / 2) + j * 16 + lr;
        bfr[j] = *(const bf16x8*)((char*)Bs + (row * 8 + (c ^ sw)) * 16);
      }
      // swapped operands -> transposed C/D layout
#pragma unroll
      for (int i = 0; i < 4; i++)
#pragma unroll
        for (int j = 0; j < JJ; j++)
          acc[i][j] = __builtin_amdgcn_mfma_f32_16x16x32_bf16(bfr[j], af[i],
                                                              acc[i][j], 0, 0, 0);
    }
    __syncthreads();
  }

  if constexpr (EPI == 0) {
    const int b = m0 >> 10, tok0 = m0 & (N_ - 1);
    if (n0 < 2 * C_) {
      // Q or K: vector bf16x4 stores, [head][tok][d]
      const int s = n0 >= C_ ? 1 : 0;
      bf16* dst = s ? o1 : o0;
#pragma unroll
      for (int i = 0; i < 4; i++) {
        const int m = m0 + wm * 64 + i * 16 + lr;
#pragma unroll
        for (int j = 0; j < JJ; j++) {
          const int rem = n0 - s * C_ + wn * (BN / 2) + j * 16 + kq * 4;
          const int h = rem >> 6, d = rem & 63;
          const f32x4 v = acc[i][j];
          bf16x4 pk = {(bf16)v[0], (bf16)v[1], (bf16)v[2], (bf16)v[3]};
          size_t head = (size_t)b * NH_ + h;
          *(bf16x4*)(dst + (head * N_ + (m & (N_ - 1))) * HD_ + d) = pk;
        }
      }
    } else {
      // V: bounce through LDS (swizzled) -> coalesced V^T rows
      bf16* tile = (bf16*)smemraw;
#pragma unroll
      for (int i = 0; i < 4; i++) {
        const int ml = wm * 64 + i * 16 + lr;
        const int mc = ml >> 3, mo = ml & 7;
#pragma unroll
        for (int j = 0; j < JJ; j++) {
          const f32x4 v = acc[i][j];
#pragma unroll
          for (int r = 0; r < 4; r++) {
            const int nl = wn * (BN / 2) + j * 16 + kq * 4 + r;
            *(bf16*)((char*)tile + nl * 256 + ((mc ^ (nl & 15)) * 16) + mo * 2) =
                (bf16)v[r];
          }
        }
      }
      __syncthreads();
      const int nl = tid >> 1, mh = (tid & 1) * 64;   // 128 rows x 2 halves
      const int vb = n0 - 2 * C_ + nl;                // channel within 768
      const size_t head = (size_t)b * NH_ + (vb >> 6);
      bf16* dst = o2 + (head * HD_ + (vb & 63)) * N_ + tok0 + mh;
#pragma unroll
      for (int c8 = 0; c8 < 8; ++c8) {
        const int c = (mh >> 3) + c8;
        bf16x8 val = *(const bf16x8*)((char*)tile + nl * 256 +
                                      ((c ^ (nl & 15)) * 16));
        *(bf16x8*)(dst + c8 * 8) = val;
      }
    }
  } else if constexpr (EPI == 3) {
#pragma unroll
    for (int j = 0; j < JJ; j++) {
      const int n = n0 + wn * (BN / 2) + j * 16 + kq * 4;
      const f32x4 bv = *(const f32x4*)(bias + n);
#pragma unroll
      for (int i = 0; i < 4; i++) {
        const int m = m0 + wm * 64 + i * 16 + lr;
        float* rp = resid + (size_t)m * C_ + n;
        f32x4 old = *(const f32x4*)rp;
        const f32x4 v = acc[i][j];
        f32x4 nw = {old[0] + v[0] + bv[0], old[1] + v[1] + bv[1],
                    old[2] + v[2] + bv[2], old[3] + v[3] + bv[3]};
        *(f32x4*)rp = nw;
      }
    }
  }
}

// ---------------------------------------------------------------------------
// Flash attention: grid (8 q-tiles, 96 heads) = 768 blocks, 256 thr.
// Wave owns 32 q-rows. 16 K-tiles of 64, double-buffered staging.
// ---------------------------------------------------------------------------
__global__ __launch_bounds__(256, 3) void flash_attn(
    const bf16* __restrict__ Qb, const bf16* __restrict__ Kb,
    const bf16* __restrict__ Vt, bf16* __restrict__ attn) {
  __shared__ __align__(16) bf16 ksm[2][64 * 64];
  __shared__ __align__(16) bf16 vsm[2][64 * 64];
  __shared__ __align__(16) bf16 psm[4][32 * 64];

  const int tid = threadIdx.x, wave = tid >> 6, lane = tid & 63;
  const int lr = lane & 15, kq = lane >> 4;
  const int head = blockIdx.y;
  const int b = head / NH_, hh = head - b * NH_;
  const int q0 = blockIdx.x * 128;
  const bf16* Qh = Qb + (size_t)head * (N_ * HD_);
  const bf16* Kh = Kb + (size_t)head * (N_ * HD_);
  const bf16* Vh = Vt + (size_t)head * (HD_ * N_);
  char* pw = (char*)&psm[wave][0];

  bf16x8 qf[2][2];
#pragma unroll
  for (int j = 0; j < 2; ++j)
#pragma unroll
    for (int kh = 0; kh < 2; ++kh)
      qf[j][kh] = *(const bf16x8*)(Qh +
                                   (size_t)(q0 + wave * 32 + j * 16 + lr) * HD_ +
                                   kh * 32 + kq * 8);

  f32x4 o[4][2];
#pragma unroll
  for (int i = 0; i < 4; i++)
#pragma unroll
    for (int j = 0; j < 2; j++) o[i][j] = (f32x4){0.f, 0.f, 0.f, 0.f};
  float mprev[2] = {-1e30f, -1e30f}, lacc[2] = {0.f, 0.f};

  auto stage = [&](int t, int bi) {
#pragma unroll
    for (int it = 0; it < 2; ++it) {
      int s = it * 256 + tid;
      int r = s >> 3, seg = (s & 7) ^ (r & 7);
      gload_lds16(Kh + (size_t)(t * 64 + r) * HD_ + seg * 8,
                  (char*)ksm[bi] + (it * 256 + wave * 64) * 16);
    }
#pragma unroll
    for (int it = 0; it < 2; ++it) {
      int s = it * 256 + tid;
      int r = s >> 3, seg = (s & 7) ^ (r & 7);
      gload_lds16(Vh + (size_t)r * N_ + t * 64 + seg * 8,
                  (char*)vsm[bi] + (it * 256 + wave * 64) * 16);
    }
  };

  stage(0, 0);

  for (int t = 0; t < 16; ++t) {
    const int bi = t & 1;
    __syncthreads();
    if (t < 15) stage(t + 1, bi ^ 1);

    f32x4 sacc[4][2];
#pragma unroll
    for (int i = 0; i < 4; ++i) {
#pragma unroll
      for (int j = 0; j < 2; ++j) sacc[i][j] = (f32x4){0.f, 0.f, 0.f, 0.f};
      int row = i * 16 + lr;
      bf16x8 kf0 = *(const bf16x8*)((char*)ksm[bi] + row * 128 +
                                    ((kq ^ (row & 7)) * 16));
      bf16x8 kf1 = *(const bf16x8*)((char*)ksm[bi] + row * 128 +
                                    (((4 + kq) ^ (row & 7)) * 16));
#pragma unroll
      for (int j = 0; j < 2; ++j) {
        sacc[i][j] = __builtin_amdgcn_mfma_f32_16x16x32_bf16(kf0, qf[j][0],
                                                             sacc[i][j], 0, 0, 0);
        sacc[i][j] = __builtin_amdgcn_mfma_f32_16x16x32_bf16(kf1, qf[j][1],
                                                             sacc[i][j], 0, 0, 0);
      }
    }

#pragma unroll
    for (int j = 0; j < 2; ++j) {
      float mx = -1e30f;
#pragma unroll
      for (int i = 0; i < 4; ++i)
#pragma unroll
        for (int r = 0; r < 4; ++r) mx = fmaxf(mx, sacc[i][j][r]);
      mx = fmaxf(mx, __shfl_xor(mx, 16));
      mx = fmaxf(mx, __shfl_xor(mx, 32));
      float mnew = fmaxf(mprev[j], mx);
      float alpha = __builtin_amdgcn_exp2f((mprev[j] - mnew) * FA_C);
      mprev[j] = mnew;
      float rs = 0.f;
      const int prow = j * 16 + lr;
#pragma unroll
      for (int i = 0; i < 4; ++i) {
        float p0 = __builtin_amdgcn_exp2f((sacc[i][j][0] - mnew) * FA_C);
        float p1 = __builtin_amdgcn_exp2f((sacc[i][j][1] - mnew) * FA_C);
        float p2 = __builtin_amdgcn_exp2f((sacc[i][j][2] - mnew) * FA_C);
        float p3 = __builtin_amdgcn_exp2f((sacc[i][j][3] - mnew) * FA_C);
        rs += (p0 + p1) + (p2 + p3);
        bf16x4 pk = {(bf16)p0, (bf16)p1, (bf16)p2, (bf16)p3};
        int c = i * 2 + (kq >> 1);
        *(bf16x4*)(pw + prow * 128 + ((c ^ (prow & 7)) * 16) + (kq & 1) * 8) = pk;
      }
      rs += __shfl_xor(rs, 16);
      rs += __shfl_xor(rs, 32);
      lacc[j] = lacc[j] * alpha + rs;
#pragma unroll
      for (int i = 0; i < 4; ++i) {
        o[i][j][0] *= alpha; o[i][j][1] *= alpha;
        o[i][j][2] *= alpha; o[i][j][3] *= alpha;
      }
    }

#pragma unroll
    for (int k0c = 0; k0c < 2; ++k0c) {
      bf16x8 pf[2];
#pragma unroll
      for (int j = 0; j < 2; ++j) {
        int prow = j * 16 + lr, c = k0c * 4 + kq;
        pf[j] = *(const bf16x8*)(pw + prow * 128 + ((c ^ (prow & 7)) * 16));
      }
#pragma unroll
      for (int i = 0; i < 4; ++i) {
        int d = i * 16 + lr, c = k0c * 4 + kq;
        bf16x8 vf = *(const bf16x8*)((char*)vsm[bi] + d * 128 +
                                     ((c ^ (d & 7)) * 16));
#pragma unroll
        for (int j = 0; j < 2; ++j)
          o[i][j] = __builtin_amdgcn_mfma_f32_16x16x32_bf16(vf, pf[j], o[i][j],
                                                            0, 0, 0);
      }
    }
  }

#pragma unroll
  for (int j = 0; j < 2; ++j) {
    float inv = 1.0f / lacc[j];
    int tok = q0 + wave * 32 + j * 16 + lr;
    bf16* op = attn + ((size_t)(b * N_ + tok)) * C_ + hh * HD_;
#pragma unroll
    for (int i = 0; i < 4; ++i) {
      bf16x4 pk = {(bf16)(o[i][j][0] * inv), (bf16)(o[i][j][1] * inv),
                   (bf16)(o[i][j][2] * inv), (bf16)(o[i][j][3] * inv)};
      *(bf16x4*)(op + i * 16 + kq * 4) = pk;
    }
  }
}

// ---------------------------------------------------------------------------
__global__ __launch_bounds__(256) void cast_all(
    const float* __restrict__ a, int na, const float* __restrict__ b, int nb,
    const float* __restrict__ c, int nc, const float* __restrict__ d,
    bf16* __restrict__ dst) {
  int i = (blockIdx.x * 256 + threadIdx.x) * 4;
  const float* src;
  int off;
  if (i < na) { src = a; off = i; }
  else if (i < na + nb) { src = b; off = i - na; }
  else if (i < na + nb + nc) { src = c; off = i - na - nb; }
  else { src = d; off = i - na - nb - nc; }
  float4 v = *(const float4*)(src + off);
  bf16x4 o = {(bf16)v.x, (bf16)v.y, (bf16)v.z, (bf16)v.w};
  *(bf16x4*)(dst + i) = o;
}

// depthwise 3x3 conv + bias + residual, fused transpose NCHW -> [B,N,C]
__global__ __launch_bounds__(256) void conv_pe_t(const float* __restrict__ x,
                                                 const float* __restrict__ cw,
                                                 const float* __restrict__ cb,
                                                 float* __restrict__ t0) {
  __shared__ float tile[32][33];
  const int h = blockIdx.x, ct = blockIdx.y, b = blockIdx.z;
  const int tid = threadIdx.x;
  const int w = tid & 31, cs = tid >> 5;
#pragma unroll
  for (int cc = cs; cc < 32; cc += 8) {
    int c = ct * 32 + cc;
    const float* xp = x + ((size_t)(b * C_ + c)) * 1024;
    const float* wp = cw + c * 9;
    float s = cb[c] + xp[h * 32 + w];
#pragma unroll
    for (int ky = 0; ky < 3; ++ky) {
      int hy = h + ky - 1;
      if ((unsigned)hy < 32u) {
#pragma unroll
        for (int kx = 0; kx < 3; ++kx) {
          int wx = w + kx - 1;
          if ((unsigned)wx < 32u) s += xp[hy * 32 + wx] * wp[ky * 3 + kx];
        }
      }
    }
    tile[cc][w] = s;
  }
  __syncthreads();
  const int cc = tid & 31;
#pragma unroll
  for (int wc = tid >> 5; wc < 32; wc += 8)
    t0[((size_t)(b * N_) + h * 32 + wc) * C_ + ct * 32 + cc] = tile[cc][wc];
}

// LayerNorm over C=768, fp32 in, bf16 out
__global__ __launch_bounds__(256) void ln_bf16(const float* __restrict__ t,
                                               const float* __restrict__ g,
                                               const float* __restrict__ be,
                                               bf16* __restrict__ out) {
  int row = blockIdx.x, tid = threadIdx.x;
  const float* p = t + (size_t)row * C_;
  float v0 = p[tid], v1 = p[tid + 256], v2 = p[tid + 512];
  __shared__ float rs[256], rq[256];
  rs[tid] = v0 + v1 + v2;
  rq[tid] = v0 * v0 + v1 * v1 + v2 * v2;
  __syncthreads();
  for (int off = 128; off; off >>= 1) {
    if (tid < off) {
      rs[tid] += rs[tid + off];
      rq[tid] += rq[tid + off];
    }
    __syncthreads();
  }
  float mu = rs[0] * (1.f / C_);
  float var = rq[0] * (1.f / C_) - mu * mu;
  float rstd = rsqrtf(var + 1e-5f);
  bf16* q = out + (size_t)row * C_;
  q[tid] = (bf16)((v0 - mu) * rstd * g[tid] + be[tid]);
  q[tid + 256] = (bf16)((v1 - mu) * rstd * g[tid + 256] + be[tid + 256]);
  q[tid + 512] = (bf16)((v2 - mu) * rstd * g[tid + 512] + be[tid + 512]);
}

// ---------------------------------------------------------------------------
extern "C" void kernel_launch(void* const* d_in, const int* in_sizes, int n_in,
                              void* d_out, int out_size, void* d_ws,
                              size_t ws_size, hipStream_t stream) {
  (void)in_sizes; (void)n_in; (void)out_size; (void)ws_size;
  const float* x      = (const float*)d_in[0];
  const float* conv_w = (const float*)d_in[1];
  const float* conv_b = (const float*)d_in[2];
  const float* ln1_g  = (const float*)d_in[3];
  const float* ln1_b  = (const float*)d_in[4];
  const float* qkv_w  = (const float*)d_in[5];
  const float* proj_w = (const float*)d_in[6];
  const float* proj_b = (const float*)d_in[7];
  const float* ln2_g  = (const float*)d_in[8];
  const float* ln2_b  = (const float*)d_in[9];
  const float* fc1_w  = (const float*)d_in[10];
  const float* fc1_b  = (const float*)d_in[11];
  const float* fc2_w  = (const float*)d_in[12];
  const float* fc2_b  = (const float*)d_in[13];
  float* out = (float*)d_out;

  char* w = (char*)d_ws;
  auto carve = [&](size_t bytes) {
    char* p = w;
    w += (bytes + 255) & ~(size_t)255;
    return p;
  };
  bf16* hid   = (bf16*)carve((size_t)NTOK * HID_ * 2);
  float* t0   = (float*)carve((size_t)NTOK * C_ * 4);
  bf16* lnout = (bf16*)carve((size_t)NTOK * C_ * 2);
  bf16* wq    = (bf16*)carve((size_t)3 * C_ * C_ * 2);
  bf16* wp    = (bf16*)carve((size_t)C_ * C_ * 2);
  bf16* w1    = (bf16*)carve((size_t)HID_ * C_ * 2);
  bf16* w2    = (bf16*)carve((size_t)C_ * HID_ * 2);
  bf16* Qb    = (bf16*)carve((size_t)NHEADS * N_ * HD_ * 2);
  bf16* Kb    = (bf16*)carve((size_t)NHEADS * N_ * HD_ * 2);
  bf16* Vt    = (bf16*)carve((size_t)NHEADS * HD_ * N_ * 2);
  bf16* attn  = (bf16*)carve((size_t)NTOK * C_ * 2);

  const int na = 3 * C_ * C_, nb = C_ * C_, nc = HID_ * C_, nd = C_ * HID_;
  cast_all<<<(na + nb + nc + nd) / 1024, 256, 0, stream>>>(
      qkv_w, na, proj_w, nb, fc1_w, nc, fc2_w, wq);

  conv_pe_t<<<dim3(32, C_ / 32, B_), 256, 0, stream>>>(x, conv_w, conv_b, t0);

  // QKV: 18 n-tiles x 64 m-stripes, XCD remap
  ln_bf16<<<NTOK, 256, 0, stream>>>(t0, ln1_g, ln1_b, lnout);
  gemm_bt<128, 0, true><<<1152, 256, 0, stream>>>(
      lnout, wq, 768, 768, 768, 18, Qb, Kb, Vt, nullptr, nullptr, nullptr);

  flash_attn<<<dim3(N_ / 128, NHEADS), 256, 0, stream>>>(Qb, Kb, Vt, attn);

  // proj: 12 n-tiles (BN=64); fc1: 256x192 pipelined (512 blocks = 2 rounds,
  // R9 control); fc2: 128x192 m201-cadence pipelined (256 blocks = 1 round)
  gemm_bt<64, 3, true><<<768, 256, 0, stream>>>(
      attn, wp, 768, 768, 768, 12, nullptr, nullptr, nullptr, t0, proj_b,
      nullptr);
  ln_bf16<<<NTOK, 256, 0, stream>>>(t0, ln2_g, ln2_b, lnout);
  gemm_fc1<<<512, 512, 0, stream>>>(lnout, w1, fc1_b, hid, 768, 768, 768,
                                    16, 4, HID_);
  gemm_fc2<<<256, 512, 0, stream>>>(hid, w2, fc2_b, t0, out, 3072, 3072, 3072);
}